// Round 4
// baseline (401.900 us; speedup 1.0000x reference)
//
#include <hip/hip_runtime.h>
#include <stdint.h>

#define C_   128
#define HW_  16384
#define CHW_ (C_*HW_)
#define N_   65536
#define E_   11
#define K_   6
#define HID_ 512

typedef __attribute__((ext_vector_type(8))) short short8;
typedef __attribute__((ext_vector_type(4))) float float4v;

// async global->LDS, 16B per lane; LDS dst is wave-uniform base + lane*16
#define GLD(g, s) __builtin_amdgcn_global_load_lds( \
    (const __attribute__((address_space(1))) unsigned int*)(uintptr_t)(g), \
    (__attribute__((address_space(3))) unsigned int*)(unsigned int)(uintptr_t)(s), 16, 0, 0)

__device__ __forceinline__ unsigned short f2bf(float f){
  union { float f; unsigned u; } v; v.f = f;
  unsigned r = v.u + 0x7fffu + ((v.u >> 16) & 1u);
  return (unsigned short)(r >> 16);
}
// gelu(v)*wr, sigmoid form: v*wr / (1 + 2^(-1.702*log2e*v)).  4 full-rate + 2 transc.
__device__ __forceinline__ float gelu_w(float v, float wr){
  float e = __builtin_amdgcn_exp2f(-2.4554673f * v);
  return v * wr * __builtin_amdgcn_rcpf(1.0f + e);
}
// pack two floats to bf16 pair (round-half-up) in one v_perm each + adds
__device__ __forceinline__ unsigned pk2(float g0, float g1){
  return __builtin_amdgcn_perm(__float_as_uint(g1) + 0x8000u,
                               __float_as_uint(g0) + 0x8000u, 0x07060302u);
}

// ---------------- build MFMA-frag-ordered bf16 weight image ----------------
// record i = e*16+hc (16KB = 1024 uint4): [0,512): W1 A-frags [mt2][ks4][lane64][j8]
//                                         [512,1024): W2 B-frags [nt8][lane64][j8]
__global__ __launch_bounds__(256) void k_convert(const float* __restrict__ w1,
                                                 const float* __restrict__ w2,
                                                 unsigned short* __restrict__ wimg,
                                                 float* __restrict__ auxsum){
  int i = blockIdx.x * 256 + threadIdx.x;   // uint4 index, grid covers 180224
  if (i < 2 * E_) auxsum[i] = 0.0f;
  if (i >= 176 * 1024) return;
  int rec = i >> 10, r = i & 1023;
  int e = rec >> 4, hc = rec & 15;
  const float* src;
  if (r < 512){
    int mt = r >> 8, ks = (r >> 6) & 3, lane = r & 63;
    int hid = hc * 32 + mt * 16 + (lane & 15);
    int c = ks * 32 + (lane >> 4) * 8;
    src = w1 + ((size_t)e * 512 + hid) * 128 + c;
  } else {
    int r2 = r - 512;
    int nt = r2 >> 6, lane = r2 & 63;
    int cc = nt * 16 + (lane & 15);
    int hd = hc * 32 + (lane >> 4) * 8;
    src = w2 + ((size_t)e * 128 + cc) * 512 + hd;
  }
  float4 a = *(const float4*)src, b = *(const float4*)(src + 4);
  union { unsigned short us[8]; uint4 v; } u;
  u.us[0] = f2bf(a.x); u.us[1] = f2bf(a.y); u.us[2] = f2bf(a.z); u.us[3] = f2bf(a.w);
  u.us[4] = f2bf(b.x); u.us[5] = f2bf(b.y); u.us[6] = f2bf(b.z); u.us[7] = f2bf(b.w);
  ((uint4*)wimg)[i] = u.v;
}

// ---------------- fused: NCHW->channels-last bf16 transpose + router ----------------
// 1024 blocks x 256 thr; 64 pixels/block. x tile staged once in LDS, consumed by both.
__global__ __launch_bounds__(256) void k_pre(const float* __restrict__ x,
                                             const float* __restrict__ gw,
                                             const float* __restrict__ gb,
                                             unsigned short* __restrict__ xcl,
                                             float* __restrict__ mask,
                                             float* __restrict__ auxsum){
  __shared__ float tt[64 * 130];
  __shared__ float g[E_ * C_];
  __shared__ float gbs[E_];
  __shared__ float ap[E_], al[E_];
  int tid = threadIdx.x;
  int pix0 = blockIdx.x * 64;
  int b = pix0 >> 14, hw0 = pix0 & 16383;
  const float* xb = x + (size_t)b * CHW_ + hw0;

  for (int i = tid; i < E_ * C_; i += 256) g[i] = gw[i];
  if (tid < E_) { gbs[tid] = gb[tid]; ap[tid] = 0.f; al[tid] = 0.f; }

  #pragma unroll 4
  for (int it = 0; it < 32; ++it){
    int flat = it * 256 + tid;
    int c = flat >> 6, p = flat & 63;
    tt[p * 130 + c] = xb[c * HW_ + p];
  }
  __syncthreads();
  // write xcl (channels-last bf16)
  #pragma unroll 4
  for (int it = 0; it < 16; ++it){
    int u = it * 256 + tid;
    int p = u >> 6, cc = u & 63;
    float f0 = tt[p * 130 + 2 * cc], f1 = tt[p * 130 + 2 * cc + 1];
    unsigned out = (unsigned)f2bf(f0) | ((unsigned)f2bf(f1) << 16);
    ((unsigned*)xcl)[(size_t)(pix0 + p) * 64 + cc] = out;
  }

  // router: 4 threads per pixel (same wave quad), each 32 channels
  int p = tid >> 2, t4 = tid & 3;
  float lg[E_];
  #pragma unroll
  for (int e = 0; e < E_; ++e) lg[e] = (t4 == 0) ? gbs[e] : 0.f;
  #pragma unroll 4
  for (int j = 0; j < 32; ++j){
    int c = t4 * 32 + j;
    float xv = tt[p * 130 + c];
    #pragma unroll
    for (int e = 0; e < E_; ++e) lg[e] = fmaf(xv, g[e * C_ + c], lg[e]);
  }
  #pragma unroll
  for (int e = 0; e < E_; ++e){
    lg[e] += __shfl_xor(lg[e], 1, 64);
    lg[e] += __shfl_xor(lg[e], 2, 64);
  }
  // softmax + top-6 (redundant across the quad; only t4==0 commits)
  float mx = lg[0];
  #pragma unroll
  for (int e = 1; e < E_; ++e) mx = fmaxf(mx, lg[e]);
  float pr[E_]; float s = 0.f;
  #pragma unroll
  for (int e = 0; e < E_; ++e){ pr[e] = expf(lg[e] - mx); s += pr[e]; }
  float inv = 1.0f / s;
  #pragma unroll
  for (int e = 0; e < E_; ++e) pr[e] *= inv;

  unsigned selmask = 0; float wsum = 0.f;
  for (int k = 0; k < K_; ++k){
    float bv = -1.f; int bi = 0;
    #pragma unroll
    for (int e = 0; e < E_; ++e){
      bool better = (((selmask >> e) & 1u) == 0u) && (pr[e] > bv);
      bv = better ? pr[e] : bv;
      bi = better ? e : bi;
    }
    selmask |= 1u << bi; wsum += bv;
  }
  float invw = 1.0f / wsum;
  if (t4 == 0){
    int pix = pix0 + p;
    #pragma unroll
    for (int e = 0; e < E_; ++e){
      bool sel = (selmask >> e) & 1u;
      mask[(size_t)pix * E_ + e] = sel ? pr[e] * invw : 0.f;
      atomicAdd(&ap[e], pr[e]);
      if (sel) atomicAdd(&al[e], 1.0f);
    }
  }
  __syncthreads();
  if (tid < E_){
    atomicAdd(&auxsum[tid], ap[tid]);
    atomicAdd(&auxsum[E_ + tid], al[tid]);
  }
}

// ---------------- fused dense MoE FFN ----------------
// 256 thr = 4 waves; 128 pixels/block; 176 iters of (expert e, 32-hid chunk hc).
// LDS 47104B -> 3 blocks/CU:
//   [0,32768)     W double buffer (16KB records via global_load_lds)
//   [32768,40960) per-wave H scratch (packed dwords, XOR-swizzled)
//   [40960,47104) mask (stride 12)
//   prologue transient: Xs @0 (32KB, consumed before first GLD)
//   epilogue: lds_t 64x129 @0 (33024B), b2t @33024 (6144B)
__global__ __launch_bounds__(256, 3) void k_ffn(const unsigned short* __restrict__ xcl,
                                                const unsigned short* __restrict__ wimg,
                                                const float* __restrict__ b1,
                                                const float* __restrict__ b2,
                                                const float* __restrict__ mask,
                                                const float* __restrict__ x,
                                                float* __restrict__ y){
  __shared__ unsigned char smem[47104];
  int tid = threadIdx.x;
  int w = tid >> 6, l = tid & 63;
  int q = l >> 4, c16 = l & 15;
  int pix0 = blockIdx.x * 128;

  // stage X tile into frag-image order (transient @0, before any W prefetch)
  unsigned short* Xs = (unsigned short*)smem;
  #pragma unroll 2
  for (int it = 0; it < 8; ++it){
    int ch = it * 256 + tid;
    int r = ch >> 4, cc = ch & 15;
    uint4 v = *(const uint4*)(xcl + ((size_t)(pix0 + r) << 7) + cc * 8);
    int gmt = r >> 4, rl = r & 15, ks = cc >> 2, qq = cc & 3;
    *(uint4*)(Xs + ((((gmt * 4 + ks) * 4 + qq) * 16 + rl) << 3)) = v;
  }
  __syncthreads();

  // X B-frags -> persistent registers (wave w owns pixel tiles 2w, 2w+1)
  short8 Xf[2][4];
  #pragma unroll
  for (int t = 0; t < 2; ++t)
    #pragma unroll
    for (int ks = 0; ks < 4; ++ks)
      Xf[t][ks] = *(const short8*)(Xs + (((((2 * w + t) * 4 + ks) * 4 + q) * 16 + c16) << 3));
  __syncthreads();   // all waves done with Xs; region becomes W dbuf

  // prefetch record 0 into buf0
  {
    const unsigned short* g = wimg + (size_t)w * 2048 + l * 8;
    unsigned char* lb = smem + w * 4096;
    #pragma unroll
    for (int t = 0; t < 4; ++t) GLD(g + t * 512, lb + t * 1024);
  }
  // stage routing mask (stride 12, zero-padded) while GLD is in flight
  float* maskl = (float*)(smem + 40960);
  for (int idx = tid; idx < 1536; idx += 256){
    int pp = idx / 12, ee = idx - pp * 12;
    maskl[idx] = (ee < 11) ? mask[(size_t)(pix0 + pp) * 11 + ee] : 0.f;
  }
  __syncthreads();   // maskl visible to all waves (full drain)

  unsigned* Hscr = (unsigned*)(smem + 32768) + w * 512;

  float4v facc[2][8];
  #pragma unroll
  for (int mt = 0; mt < 2; ++mt)
    #pragma unroll
    for (int nt = 0; nt < 8; ++nt) facc[mt][nt] = (float4v){0.f,0.f,0.f,0.f};

  float4 bn0 = *(const float4*)(b1 + q * 4);
  float4 bn1 = *(const float4*)(b1 + 16 + q * 4);
  float wr0 = 0.f, wr1 = 0.f;
  int sw = (c16 + (c16 >> 2)) & 3;

  #pragma unroll 1
  for (int i = 0; i < 176; ++i){
    asm volatile("s_waitcnt vmcnt(0)" ::: "memory");
    __builtin_amdgcn_s_barrier();
    // prefetch next record into the other buffer (lands during compute(i))
    if (i + 1 < 176){
      const unsigned short* g = wimg + (size_t)(i + 1) * 8192 + w * 2048 + l * 8;
      unsigned char* lb = smem + (((i + 1) & 1) << 14) + w * 4096;
      #pragma unroll
      for (int t = 0; t < 4; ++t) GLD(g + t * 512, lb + t * 1024);
    }
    __builtin_amdgcn_sched_barrier(0);
    const unsigned short* wb = (const unsigned short*)(smem + ((i & 1) << 14));

    if ((i & 15) == 0){   // new expert: routing weights (uniform branch)
      int e = i >> 4;
      wr0 = maskl[((2 * w + 0) * 16 + c16) * 12 + e];
      wr1 = maskl[((2 * w + 1) * 16 + c16) * 12 + e];
    }
    float4 bc0 = bn0, bc1 = bn1;
    if (i + 1 < 176){   // software-prefetch next chunk's b1
      bn0 = *(const float4*)(b1 + (i + 1) * 32 + q * 4);
      bn1 = *(const float4*)(b1 + (i + 1) * 32 + 16 + q * 4);
    }

    // GEMM1 (transposed): HT[32 hid][32 pix] per wave; bias folded into C-init
    float4v h00 = {bc0.x, bc0.y, bc0.z, bc0.w};
    float4v h01 = h00;
    float4v h10 = {bc1.x, bc1.y, bc1.z, bc1.w};
    float4v h11 = h10;
    #pragma unroll
    for (int ks = 0; ks < 4; ++ks){
      short8 a0 = *(const short8*)(wb + ks * 512 + l * 8);
      short8 a1 = *(const short8*)(wb + (4 + ks) * 512 + l * 8);
      h00 = __builtin_amdgcn_mfma_f32_16x16x32_bf16(a0, Xf[0][ks], h00, 0, 0, 0);
      h01 = __builtin_amdgcn_mfma_f32_16x16x32_bf16(a0, Xf[1][ks], h01, 0, 0, 0);
      h10 = __builtin_amdgcn_mfma_f32_16x16x32_bf16(a1, Xf[0][ks], h10, 0, 0, 0);
      h11 = __builtin_amdgcn_mfma_f32_16x16x32_bf16(a1, Xf[1][ks], h11, 0, 0, 0);
    }

    // gelu * mask, pack bf16 pairs, wave-local swizzled LDS (C-layout -> A-layout)
    #pragma unroll
    for (int mh = 0; mh < 2; ++mh){
      float4v hv0 = (mh == 0) ? h00 : h10;
      float4v hv1 = (mh == 0) ? h01 : h11;
      int grp = (((mh * 2 + (q >> 1)) ^ sw) << 2);
      int lo0 = (q * 2) & 3, lo1 = (q * 2 + 1) & 3;
      Hscr[c16 * 16 + grp + lo0]        = pk2(gelu_w(hv0[0], wr0), gelu_w(hv0[1], wr0));
      Hscr[c16 * 16 + grp + lo1]        = pk2(gelu_w(hv0[2], wr0), gelu_w(hv0[3], wr0));
      Hscr[(16 + c16) * 16 + grp + lo0] = pk2(gelu_w(hv1[0], wr1), gelu_w(hv1[1], wr1));
      Hscr[(16 + c16) * 16 + grp + lo1] = pk2(gelu_w(hv1[2], wr1), gelu_w(hv1[3], wr1));
    }
    // read back as GEMM2 A-frags (same wave; compiler inserts the minimal lgkm wait)
    short8 af0 = *(const short8*)(Hscr + c16 * 16 + ((q ^ sw) << 2));
    short8 af1 = *(const short8*)(Hscr + (16 + c16) * 16 + ((q ^ sw) << 2));

    // GEMM2: facc += H[32pix x 32hid] * W2c^T
    #pragma unroll
    for (int nt = 0; nt < 8; ++nt){
      short8 bf = *(const short8*)(wb + 4096 + nt * 512 + l * 8);
      facc[0][nt] = __builtin_amdgcn_mfma_f32_16x16x32_bf16(af0, bf, facc[0][nt], 0, 0, 0);
      facc[1][nt] = __builtin_amdgcn_mfma_f32_16x16x32_bf16(af1, bf, facc[1][nt], 0, 0, 0);
    }
  }

  // ---- epilogue: transpose to NCHW, add x and sum_e mask*b2 ----
  __syncthreads();
  float* lds_t = (float*)smem;               // 64 x 129 fp32 = 33024B
  float* b2t   = (float*)(smem + 33024);     // [c][12] transposed, zero-padded
  for (int idx = tid; idx < 1536; idx += 256){
    int cc = idx / 12, ee = idx - cc * 12;
    b2t[idx] = (ee < 11) ? b2[ee * 128 + cc] : 0.f;
  }

  #pragma unroll 1
  for (int h = 0; h < 2; ++h){
    __syncthreads();
    if ((w >> 1) == h){
      int wh = w & 1;
      #pragma unroll
      for (int mt = 0; mt < 2; ++mt)
        #pragma unroll
        for (int nt = 0; nt < 8; ++nt)
          #pragma unroll
          for (int rg = 0; rg < 4; ++rg)
            lds_t[(wh * 32 + mt * 16 + q * 4 + rg) * 129 + nt * 16 + c16] = facc[mt][nt][rg];
    }
    __syncthreads();
    int p = tid & 63;
    int row = h * 64 + p;
    float4 m0 = *(const float4*)(maskl + row * 12);
    float4 m1 = *(const float4*)(maskl + row * 12 + 4);
    float4 m2 = *(const float4*)(maskl + row * 12 + 8);
    int pix = pix0 + row; int bb = pix >> 14, hw = pix & 16383;
    #pragma unroll 4
    for (int it = 0; it < 32; ++it){
      int c = w * 32 + it;
      float acc = lds_t[p * 129 + c];
      float4 b0 = *(const float4*)(b2t + c * 12);
      float4 bq1 = *(const float4*)(b2t + c * 12 + 4);
      float4 bq2 = *(const float4*)(b2t + c * 12 + 8);
      acc = fmaf(m0.x, b0.x, acc);  acc = fmaf(m0.y, b0.y, acc);
      acc = fmaf(m0.z, b0.z, acc);  acc = fmaf(m0.w, b0.w, acc);
      acc = fmaf(m1.x, bq1.x, acc); acc = fmaf(m1.y, bq1.y, acc);
      acc = fmaf(m1.z, bq1.z, acc); acc = fmaf(m1.w, bq1.w, acc);
      acc = fmaf(m2.x, bq2.x, acc); acc = fmaf(m2.y, bq2.y, acc);
      acc = fmaf(m2.z, bq2.z, acc);
      size_t idx2 = (size_t)bb * CHW_ + (size_t)c * HW_ + hw;
      y[idx2] = x[idx2] + acc;
    }
  }
}

// ---------------- aux loss ----------------
__global__ void k_aux(const float* __restrict__ auxsum, float* __restrict__ out){
  if (threadIdx.x == 0 && blockIdx.x == 0){
    float s = 0.f;
    const float invN = 1.0f / (float)N_;
    for (int e = 0; e < E_; ++e)
      s += (auxsum[e] * invN) * (auxsum[E_ + e] * invN);
    out[(size_t)N_ * C_] = (float)E_ * s;
  }
}

extern "C" void kernel_launch(void* const* d_in, const int* in_sizes, int n_in,
                              void* d_out, int out_size, void* d_ws, size_t ws_size,
                              hipStream_t stream){
  const float* x  = (const float*)d_in[0];
  const float* gw = (const float*)d_in[1];
  const float* gb = (const float*)d_in[2];
  const float* w1 = (const float*)d_in[3];
  const float* b1 = (const float*)d_in[4];
  const float* w2 = (const float*)d_in[5];
  const float* b2 = (const float*)d_in[6];
  float* y = (float*)d_out;
  char* ws = (char*)d_ws;

  unsigned short* xcl  = (unsigned short*)ws;                   // 16,777,216 B
  unsigned short* wimg = (unsigned short*)(ws + 16777216);      //  2,883,584 B
  float* mask   = (float*)(ws + 19660800);                      //  2,883,584 B
  float* auxsum = (float*)(ws + 22544384);                      //         88 B

  hipLaunchKernelGGL(k_convert, dim3(704),  dim3(256), 0, stream, w1, w2, wimg, auxsum);
  hipLaunchKernelGGL(k_pre,     dim3(1024), dim3(256), 0, stream, x, gw, gb, xcl, mask, auxsum);
  hipLaunchKernelGGL(k_ffn,     dim3(512),  dim3(256), 0, stream, xcl, wimg, b1, b2, mask, x, y);
  hipLaunchKernelGGL(k_aux,     dim3(1),    dim3(64),  0, stream, auxsum, y);
}

// Round 5
// 363.459 us; speedup vs baseline: 1.1058x; 1.1058x over previous
//
#include <hip/hip_runtime.h>
#include <stdint.h>

#define C_   128
#define HW_  16384
#define CHW_ (C_*HW_)
#define N_   65536
#define E_   11
#define K_   6
#define HID_ 512

typedef __attribute__((ext_vector_type(8))) short short8;
typedef __attribute__((ext_vector_type(4))) float float4v;

// async global->LDS, 16B per lane; LDS dst is wave-uniform base + lane*16
#define GLD(g, s) __builtin_amdgcn_global_load_lds( \
    (const __attribute__((address_space(1))) unsigned int*)(uintptr_t)(g), \
    (__attribute__((address_space(3))) unsigned int*)(unsigned int)(uintptr_t)(s), 16, 0, 0)

__device__ __forceinline__ unsigned short f2bf(float f){
  union { float f; unsigned u; } v; v.f = f;
  unsigned r = v.u + 0x7fffu + ((v.u >> 16) & 1u);
  return (unsigned short)(r >> 16);
}
// gelu(v)*wr via odd deg-7 poly fit of erf(t/sqrt2) on |t|<=2.5 (max err ~2.4e-3).
// 9 full-rate VALU ops, no transcendentals.
__device__ __forceinline__ float gelu_w(float v, float wr){
  float t = __builtin_amdgcn_fmed3f(v, -2.5f, 2.5f);
  float u = t * t;
  float s = fmaf(u, fmaf(u, fmaf(u, -0.00076957f, 0.0147811f), -0.126434f), 0.795742f);
  float p = t * s;                       // ~erf(t/sqrt(2))
  return (v * wr) * fmaf(0.5f, p, 0.5f);
}
// pack two floats to bf16 pair (round-half-up) in one v_perm each + adds
__device__ __forceinline__ unsigned pk2(float g0, float g1){
  return __builtin_amdgcn_perm(__float_as_uint(g1) + 0x8000u,
                               __float_as_uint(g0) + 0x8000u, 0x07060302u);
}

// ---------------- build MFMA-frag-ordered bf16 weight image ----------------
// record i = e*16+hc (16KB = 1024 uint4): [0,512): W1 A-frags [mt2][ks4][lane64][j8]
//                                         [512,1024): W2 B-frags [nt8][lane64][j8]
__global__ __launch_bounds__(256) void k_convert(const float* __restrict__ w1,
                                                 const float* __restrict__ w2,
                                                 unsigned short* __restrict__ wimg,
                                                 float* __restrict__ auxsum){
  int i = blockIdx.x * 256 + threadIdx.x;   // uint4 index, grid covers 180224
  if (i < 2 * E_) auxsum[i] = 0.0f;
  if (i >= 176 * 1024) return;
  int rec = i >> 10, r = i & 1023;
  int e = rec >> 4, hc = rec & 15;
  const float* src;
  if (r < 512){
    int mt = r >> 8, ks = (r >> 6) & 3, lane = r & 63;
    int hid = hc * 32 + mt * 16 + (lane & 15);
    int c = ks * 32 + (lane >> 4) * 8;
    src = w1 + ((size_t)e * 512 + hid) * 128 + c;
  } else {
    int r2 = r - 512;
    int nt = r2 >> 6, lane = r2 & 63;
    int cc = nt * 16 + (lane & 15);
    int hd = hc * 32 + (lane >> 4) * 8;
    src = w2 + ((size_t)e * 128 + cc) * 512 + hd;
  }
  float4 a = *(const float4*)src, b = *(const float4*)(src + 4);
  union { unsigned short us[8]; uint4 v; } u;
  u.us[0] = f2bf(a.x); u.us[1] = f2bf(a.y); u.us[2] = f2bf(a.z); u.us[3] = f2bf(a.w);
  u.us[4] = f2bf(b.x); u.us[5] = f2bf(b.y); u.us[6] = f2bf(b.z); u.us[7] = f2bf(b.w);
  ((uint4*)wimg)[i] = u.v;
}

// ---------------- fused: NCHW->channels-last bf16 transpose + router ----------------
__global__ __launch_bounds__(256) void k_pre(const float* __restrict__ x,
                                             const float* __restrict__ gw,
                                             const float* __restrict__ gb,
                                             unsigned short* __restrict__ xcl,
                                             float* __restrict__ mask,
                                             float* __restrict__ auxsum){
  __shared__ float tt[64 * 130];
  __shared__ float g[E_ * C_];
  __shared__ float gbs[E_];
  __shared__ float ap[E_], al[E_];
  int tid = threadIdx.x;
  int pix0 = blockIdx.x * 64;
  int b = pix0 >> 14, hw0 = pix0 & 16383;
  const float* xb = x + (size_t)b * CHW_ + hw0;

  for (int i = tid; i < E_ * C_; i += 256) g[i] = gw[i];
  if (tid < E_) { gbs[tid] = gb[tid]; ap[tid] = 0.f; al[tid] = 0.f; }

  #pragma unroll 4
  for (int it = 0; it < 32; ++it){
    int flat = it * 256 + tid;
    int c = flat >> 6, p = flat & 63;
    tt[p * 130 + c] = xb[c * HW_ + p];
  }
  __syncthreads();
  #pragma unroll 4
  for (int it = 0; it < 16; ++it){
    int u = it * 256 + tid;
    int p = u >> 6, cc = u & 63;
    float f0 = tt[p * 130 + 2 * cc], f1 = tt[p * 130 + 2 * cc + 1];
    unsigned out = (unsigned)f2bf(f0) | ((unsigned)f2bf(f1) << 16);
    ((unsigned*)xcl)[(size_t)(pix0 + p) * 64 + cc] = out;
  }

  // router: 4 threads per pixel (same wave quad), each 32 channels
  int p = tid >> 2, t4 = tid & 3;
  float lg[E_];
  #pragma unroll
  for (int e = 0; e < E_; ++e) lg[e] = (t4 == 0) ? gbs[e] : 0.f;
  #pragma unroll 4
  for (int j = 0; j < 32; ++j){
    int c = t4 * 32 + j;
    float xv = tt[p * 130 + c];
    #pragma unroll
    for (int e = 0; e < E_; ++e) lg[e] = fmaf(xv, g[e * C_ + c], lg[e]);
  }
  #pragma unroll
  for (int e = 0; e < E_; ++e){
    lg[e] += __shfl_xor(lg[e], 1, 64);
    lg[e] += __shfl_xor(lg[e], 2, 64);
  }
  float mx = lg[0];
  #pragma unroll
  for (int e = 1; e < E_; ++e) mx = fmaxf(mx, lg[e]);
  float pr[E_]; float s = 0.f;
  #pragma unroll
  for (int e = 0; e < E_; ++e){ pr[e] = expf(lg[e] - mx); s += pr[e]; }
  float inv = 1.0f / s;
  #pragma unroll
  for (int e = 0; e < E_; ++e) pr[e] *= inv;

  unsigned selmask = 0; float wsum = 0.f;
  for (int k = 0; k < K_; ++k){
    float bv = -1.f; int bi = 0;
    #pragma unroll
    for (int e = 0; e < E_; ++e){
      bool better = (((selmask >> e) & 1u) == 0u) && (pr[e] > bv);
      bv = better ? pr[e] : bv;
      bi = better ? e : bi;
    }
    selmask |= 1u << bi; wsum += bv;
  }
  float invw = 1.0f / wsum;
  if (t4 == 0){
    int pix = pix0 + p;
    #pragma unroll
    for (int e = 0; e < E_; ++e){
      bool sel = (selmask >> e) & 1u;
      mask[(size_t)pix * E_ + e] = sel ? pr[e] * invw : 0.f;
      atomicAdd(&ap[e], pr[e]);
      if (sel) atomicAdd(&al[e], 1.0f);
    }
  }
  __syncthreads();
  if (tid < E_){
    atomicAdd(&auxsum[tid], ap[tid]);
    atomicAdd(&auxsum[E_ + tid], al[tid]);
  }
}

// ---------------- fused dense MoE FFN (+ aux-loss write) ----------------
// 256 thr = 4 waves; 128 pixels/block; 176 iters of (expert e, 32-hid chunk hc).
// LDS 63488B:
//   [0,49152)      W TRIPLE buffer (16KB records via global_load_lds, prefetch dist 2)
//   [49152,57344)  per-wave H scratch (packed dwords, XOR-swizzled)
//   [57344,63488)  mask (stride 12)
//   prologue transient: Xs @0 (32KB, consumed before first GLD)
//   epilogue: lds_t 64x129 @0 (33024B), b2t @33024 (6144B)
__global__ __launch_bounds__(256, 2) void k_ffn(const unsigned short* __restrict__ xcl,
                                                const unsigned short* __restrict__ wimg,
                                                const float* __restrict__ b1,
                                                const float* __restrict__ b2,
                                                const float* __restrict__ mask,
                                                const float* __restrict__ auxsum,
                                                const float* __restrict__ x,
                                                float* __restrict__ y){
  __shared__ unsigned char smem[63488];
  int tid = threadIdx.x;
  int w = tid >> 6, l = tid & 63;
  int q = l >> 4, c16 = l & 15;
  int pix0 = blockIdx.x * 128;

  // aux loss (auxsum complete: k_pre is stream-ordered before us)
  if (blockIdx.x == 0 && tid == 0){
    float s = 0.f;
    const float invN = 1.0f / (float)N_;
    for (int e = 0; e < E_; ++e)
      s += (auxsum[e] * invN) * (auxsum[E_ + e] * invN);
    y[(size_t)N_ * C_] = (float)E_ * s;
  }

  // stage X tile into frag-image order (transient @0, before any W prefetch)
  unsigned short* Xs = (unsigned short*)smem;
  #pragma unroll 2
  for (int it = 0; it < 8; ++it){
    int ch = it * 256 + tid;
    int r = ch >> 4, cc = ch & 15;
    uint4 v = *(const uint4*)(xcl + ((size_t)(pix0 + r) << 7) + cc * 8);
    int gmt = r >> 4, rl = r & 15, ks = cc >> 2, qq = cc & 3;
    *(uint4*)(Xs + ((((gmt * 4 + ks) * 4 + qq) * 16 + rl) << 3)) = v;
  }
  __syncthreads();

  // X B-frags -> persistent registers (wave w owns pixel tiles 2w, 2w+1)
  short8 Xf[2][4];
  #pragma unroll
  for (int t = 0; t < 2; ++t)
    #pragma unroll
    for (int ks = 0; ks < 4; ++ks)
      Xf[t][ks] = *(const short8*)(Xs + (((((2 * w + t) * 4 + ks) * 4 + q) * 16 + c16) << 3));
  __syncthreads();   // all waves done with Xs; region becomes W triple buffer

  // prefetch records 0 and 1 into buf0/buf1
  #pragma unroll
  for (int rr = 0; rr < 2; ++rr){
    const unsigned short* g = wimg + (size_t)rr * 8192 + w * 2048 + l * 8;
    unsigned char* lb = smem + rr * 16384 + w * 4096;
    #pragma unroll
    for (int t = 0; t < 4; ++t) GLD(g + t * 512, lb + t * 1024);
  }
  // stage routing mask (stride 12, zero-padded) while GLDs are in flight
  float* maskl = (float*)(smem + 57344);
  for (int idx = tid; idx < 1536; idx += 256){
    int pp = idx / 12, ee = idx - pp * 12;
    maskl[idx] = (ee < 11) ? mask[(size_t)(pix0 + pp) * 11 + ee] : 0.f;
  }
  float4 bn0 = *(const float4*)(b1 + q * 4);
  float4 bn1 = *(const float4*)(b1 + 16 + q * 4);
  __syncthreads();   // full drain: buf0/buf1 + maskl ready

  unsigned* Hscr = (unsigned*)(smem + 49152) + w * 512;

  float4v facc[2][8];
  #pragma unroll
  for (int mt = 0; mt < 2; ++mt)
    #pragma unroll
    for (int nt = 0; nt < 8; ++nt) facc[mt][nt] = (float4v){0.f,0.f,0.f,0.f};

  float wr0 = 0.f, wr1 = 0.f;
  int sw = (c16 + (c16 >> 2)) & 3;
  int bufA = 0;   // i % 3

  #pragma unroll 1
  for (int i = 0; i < 176; ++i){
    // drain only this wave's GLD(i) (oldest 4 of <=10 outstanding); buffers i+1,i+2 stay in flight
    asm volatile("s_waitcnt vmcnt(6)" ::: "memory");
    __builtin_amdgcn_s_barrier();
    // prefetch record i+2 (clamped tail re-issues keep vmcnt geometry uniform; same bytes -> benign)
    {
      int pf = (i + 2 <= 175) ? (i + 2) : 175;
      const unsigned short* g = wimg + (size_t)pf * 8192 + w * 2048 + l * 8;
      unsigned char* lb = smem + (pf % 3) * 16384 + w * 4096;
      #pragma unroll
      for (int t = 0; t < 4; ++t) GLD(g + t * 512, lb + t * 1024);
    }
    // b1 software prefetch (unconditional, clamped)
    float4 bc0 = bn0, bc1 = bn1;
    {
      int nb = (i + 1 <= 175) ? (i + 1) : 175;
      bn0 = *(const float4*)(b1 + nb * 32 + q * 4);
      bn1 = *(const float4*)(b1 + nb * 32 + 16 + q * 4);
    }
    __builtin_amdgcn_sched_barrier(0);
    const unsigned short* wb = (const unsigned short*)(smem + bufA * 16384);
    bufA = (bufA == 2) ? 0 : bufA + 1;

    if ((i & 15) == 0){   // new expert: routing weights (uniform branch)
      int e = i >> 4;
      wr0 = maskl[((2 * w + 0) * 16 + c16) * 12 + e];
      wr1 = maskl[((2 * w + 1) * 16 + c16) * 12 + e];
    }

    // GEMM1 (transposed): HT[32 hid][32 pix] per wave; bias folded into C-init
    float4v h00 = {bc0.x, bc0.y, bc0.z, bc0.w};
    float4v h01 = h00;
    float4v h10 = {bc1.x, bc1.y, bc1.z, bc1.w};
    float4v h11 = h10;
    #pragma unroll
    for (int ks = 0; ks < 4; ++ks){
      short8 a0 = *(const short8*)(wb + ks * 512 + l * 8);
      short8 a1 = *(const short8*)(wb + (4 + ks) * 512 + l * 8);
      h00 = __builtin_amdgcn_mfma_f32_16x16x32_bf16(a0, Xf[0][ks], h00, 0, 0, 0);
      h01 = __builtin_amdgcn_mfma_f32_16x16x32_bf16(a0, Xf[1][ks], h01, 0, 0, 0);
      h10 = __builtin_amdgcn_mfma_f32_16x16x32_bf16(a1, Xf[0][ks], h10, 0, 0, 0);
      h11 = __builtin_amdgcn_mfma_f32_16x16x32_bf16(a1, Xf[1][ks], h11, 0, 0, 0);
    }

    // gelu * mask, pack bf16, wave-local swizzled LDS (C-layout -> A-layout), b64 writes
    #pragma unroll
    for (int mh = 0; mh < 2; ++mh){
      float4v hv0 = (mh == 0) ? h00 : h10;
      float4v hv1 = (mh == 0) ? h01 : h11;
      int grp = (((mh * 2 + (q >> 1)) ^ sw) << 2);
      int lo0 = (q * 2) & 3;   // even; lo1 = lo0+1 -> contiguous pair
      uint2 d0, d1;
      d0.x = pk2(gelu_w(hv0[0], wr0), gelu_w(hv0[1], wr0));
      d0.y = pk2(gelu_w(hv0[2], wr0), gelu_w(hv0[3], wr0));
      d1.x = pk2(gelu_w(hv1[0], wr1), gelu_w(hv1[1], wr1));
      d1.y = pk2(gelu_w(hv1[2], wr1), gelu_w(hv1[3], wr1));
      *(uint2*)(Hscr + c16 * 16 + grp + lo0)        = d0;
      *(uint2*)(Hscr + (16 + c16) * 16 + grp + lo0) = d1;
    }
    // read back as GEMM2 A-frags (same wave; DS in-order, compiler inserts minimal lgkm wait)
    short8 af0 = *(const short8*)(Hscr + c16 * 16 + ((q ^ sw) << 2));
    short8 af1 = *(const short8*)(Hscr + (16 + c16) * 16 + ((q ^ sw) << 2));

    // GEMM2: facc += H[32pix x 32hid] * W2c^T
    #pragma unroll
    for (int nt = 0; nt < 8; ++nt){
      short8 bf = *(const short8*)(wb + 4096 + nt * 512 + l * 8);
      facc[0][nt] = __builtin_amdgcn_mfma_f32_16x16x32_bf16(af0, bf, facc[0][nt], 0, 0, 0);
      facc[1][nt] = __builtin_amdgcn_mfma_f32_16x16x32_bf16(af1, bf, facc[1][nt], 0, 0, 0);
    }
  }

  // ---- epilogue: transpose to NCHW, add x and sum_e mask*b2 ----
  __syncthreads();   // full drain incl. trailing GLD re-issues (they target [16K,32K) = lds_t area)
  float* lds_t = (float*)smem;               // 64 x 129 fp32 = 33024B
  float* b2t   = (float*)(smem + 33024);     // [c][12] transposed, zero-padded
  for (int idx = tid; idx < 1536; idx += 256){
    int cc = idx / 12, ee = idx - cc * 12;
    b2t[idx] = (ee < 11) ? b2[ee * 128 + cc] : 0.f;
  }

  #pragma unroll 1
  for (int h = 0; h < 2; ++h){
    __syncthreads();
    if ((w >> 1) == h){
      int wh = w & 1;
      #pragma unroll
      for (int mt = 0; mt < 2; ++mt)
        #pragma unroll
        for (int nt = 0; nt < 8; ++nt)
          #pragma unroll
          for (int rg = 0; rg < 4; ++rg)
            lds_t[(wh * 32 + mt * 16 + q * 4 + rg) * 129 + nt * 16 + c16] = facc[mt][nt][rg];
    }
    __syncthreads();
    int p = tid & 63;
    int row = h * 64 + p;
    float4 m0 = *(const float4*)(maskl + row * 12);
    float4 m1 = *(const float4*)(maskl + row * 12 + 4);
    float4 m2 = *(const float4*)(maskl + row * 12 + 8);
    int pix = pix0 + row; int bb = pix >> 14, hw = pix & 16383;
    #pragma unroll 4
    for (int it = 0; it < 32; ++it){
      int c = w * 32 + it;
      float acc = lds_t[p * 129 + c];
      float4 b0 = *(const float4*)(b2t + c * 12);
      float4 bq1 = *(const float4*)(b2t + c * 12 + 4);
      float4 bq2 = *(const float4*)(b2t + c * 12 + 8);
      acc = fmaf(m0.x, b0.x, acc);  acc = fmaf(m0.y, b0.y, acc);
      acc = fmaf(m0.z, b0.z, acc);  acc = fmaf(m0.w, b0.w, acc);
      acc = fmaf(m1.x, bq1.x, acc); acc = fmaf(m1.y, bq1.y, acc);
      acc = fmaf(m1.z, bq1.z, acc); acc = fmaf(m1.w, bq1.w, acc);
      acc = fmaf(m2.x, bq2.x, acc); acc = fmaf(m2.y, bq2.y, acc);
      acc = fmaf(m2.z, bq2.z, acc);
      size_t idx2 = (size_t)bb * CHW_ + (size_t)c * HW_ + hw;
      y[idx2] = x[idx2] + acc;
    }
  }
}

extern "C" void kernel_launch(void* const* d_in, const int* in_sizes, int n_in,
                              void* d_out, int out_size, void* d_ws, size_t ws_size,
                              hipStream_t stream){
  const float* x  = (const float*)d_in[0];
  const float* gw = (const float*)d_in[1];
  const float* gb = (const float*)d_in[2];
  const float* w1 = (const float*)d_in[3];
  const float* b1 = (const float*)d_in[4];
  const float* w2 = (const float*)d_in[5];
  const float* b2 = (const float*)d_in[6];
  float* y = (float*)d_out;
  char* ws = (char*)d_ws;

  unsigned short* xcl  = (unsigned short*)ws;                   // 16,777,216 B
  unsigned short* wimg = (unsigned short*)(ws + 16777216);      //  2,883,584 B
  float* mask   = (float*)(ws + 19660800);                      //  2,883,584 B
  float* auxsum = (float*)(ws + 22544384);                      //         88 B

  hipLaunchKernelGGL(k_convert, dim3(704),  dim3(256), 0, stream, w1, w2, wimg, auxsum);
  hipLaunchKernelGGL(k_pre,     dim3(1024), dim3(256), 0, stream, x, gw, gb, xcl, mask, auxsum);
  hipLaunchKernelGGL(k_ffn,     dim3(512),  dim3(256), 0, stream, xcl, wimg, b1, b2, mask, auxsum, x, y);
}